// Round 1
// baseline (553.529 us; speedup 1.0000x reference)
//
#include <hip/hip_runtime.h>

static constexpr int FEAT = 128;
static constexpr int SCAN_B = 256;

// ---------------- CSR build ----------------

__global__ void k_zero_int(int* __restrict__ p, int n) {
  int i = blockIdx.x * blockDim.x + threadIdx.x;
  if (i < n) p[i] = 0;
}

__global__ void k_degree(const int* __restrict__ dst, int E, int* __restrict__ deg) {
  int e = blockIdx.x * blockDim.x + threadIdx.x;
  if (e < E) atomicAdd(&deg[dst[e]], 1);
}

__global__ void k_scan_local(const int* __restrict__ deg, int N,
                             int* __restrict__ off, int* __restrict__ aux) {
  __shared__ int s[SCAN_B];
  int t = threadIdx.x;
  int i = blockIdx.x * SCAN_B + t;
  int v = (i < N) ? deg[i] : 0;
  s[t] = v;
  __syncthreads();
  for (int d = 1; d < SCAN_B; d <<= 1) {
    int add = (t >= d) ? s[t - d] : 0;
    __syncthreads();
    s[t] += add;
    __syncthreads();
  }
  if (i < N) off[i] = s[t] - v;            // exclusive within block
  if (t == SCAN_B - 1) aux[blockIdx.x] = s[t];
}

__global__ void k_scan_aux(int* __restrict__ aux, int nb) {
  __shared__ int s[SCAN_B];
  int t = threadIdx.x;
  int v = (t < nb) ? aux[t] : 0;
  s[t] = v;
  __syncthreads();
  for (int d = 1; d < SCAN_B; d <<= 1) {
    int add = (t >= d) ? s[t - d] : 0;
    __syncthreads();
    s[t] += add;
    __syncthreads();
  }
  if (t < nb) aux[t] = s[t] - v;           // exclusive block offsets
}

__global__ void k_finish(int* __restrict__ off, const int* __restrict__ aux,
                         const int* __restrict__ deg, float* __restrict__ dinv,
                         int* __restrict__ cursor, int N, int E) {
  int i = blockIdx.x * blockDim.x + threadIdx.x;
  if (i < N) {
    int o = off[i] + aux[i >> 8];          // blockDim == SCAN_B == 256
    off[i] = o;
    cursor[i] = o;
    dinv[i] = rsqrtf((float)(deg[i] + 1)); // degree over A+I
  }
  if (i == 0) off[N] = E;
}

__global__ void k_fill(const int* __restrict__ src, const int* __restrict__ dst, int E,
                       int* __restrict__ cursor, int* __restrict__ csr) {
  int e = blockIdx.x * blockDim.x + threadIdx.x;
  if (e < E) {
    int p = atomicAdd(&cursor[dst[e]], 1);
    csr[p] = src[e];
  }
}

// ---------------- dense GEMM: Y[r] = dinv[r] * (X[r] @ W) ----------------
// W fully resident in LDS (64 KiB). 256 threads: 16 rows x 16 col-groups of 8.
__global__ __launch_bounds__(256) void k_gemm_scaled(
    const float* __restrict__ X, const float* __restrict__ W,
    const float* __restrict__ dinv, float* __restrict__ Y, int N) {
  __shared__ float ws[FEAT * FEAT];        // 65536 bytes exactly
  {
    const float4* W4 = (const float4*)W;
    float4* ws4 = (float4*)ws;
    for (int i = threadIdx.x; i < FEAT * FEAT / 4; i += 256) ws4[i] = W4[i];
  }
  __syncthreads();
  const int ct = threadIdx.x & 15;         // col group: cols ct*8 .. ct*8+7
  const int rl = threadIdx.x >> 4;         // row-in-tile 0..15
  const int ntiles = (N + 15) / 16;
  for (int tile = blockIdx.x; tile < ntiles; tile += gridDim.x) {
    const int r = tile * 16 + rl;
    if (r >= N) continue;
    const float* xr = X + (size_t)r * FEAT;
    float acc[8];
#pragma unroll
    for (int j = 0; j < 8; j++) acc[j] = 0.f;
#pragma unroll 4
    for (int k = 0; k < FEAT; k++) {
      float xv = xr[k];                    // 16-lane broadcast via L1
      const float* wr = ws + k * FEAT + ct * 8;
#pragma unroll
      for (int j = 0; j < 8; j++) acc[j] += xv * wr[j];
    }
    float dn = dinv[r];
    float4* yp = (float4*)(Y + (size_t)r * FEAT + ct * 8);
    yp[0] = make_float4(acc[0] * dn, acc[1] * dn, acc[2] * dn, acc[3] * dn);
    yp[1] = make_float4(acc[4] * dn, acc[5] * dn, acc[6] * dn, acc[7] * dn);
  }
}

// ---------------- propagation: h[n] = relu(dinv[n]*(sum_in xws[s] + xws[n]) + b) --------
// xws is already dinv-scaled (fused in GEMM epilogue), so inner loop is one gather.
__global__ __launch_bounds__(256) void k_prop(
    const float* __restrict__ xws, const int* __restrict__ off,
    const int* __restrict__ csr, const float* __restrict__ dinv,
    const float* __restrict__ bias, float* __restrict__ hout, int N) {
  int n = blockIdx.x * 2 + (threadIdx.x >> 7);
  int j = threadIdx.x & 127;
  if (n >= N) return;
  int i0 = off[n], i1 = off[n + 1];
  float acc = 0.f;
  for (int i = i0; i < i1; i++) {
    int s = csr[i];                        // wave-uniform load
    acc += xws[(size_t)s * FEAT + j];      // coalesced 512B row gather
  }
  float dn = dinv[n];
  float v = dn * (acc + xws[(size_t)n * FEAT + j]) + bias[j];
  hout[(size_t)n * FEAT + j] = v > 0.f ? v : 0.f;
}

// ---------------- pooling: per-graph mean over sorted batch ----------------
__device__ __forceinline__ int lower_bound(const int* __restrict__ a, int n, int v) {
  int lo = 0, hi = n;
  while (lo < hi) { int m = (lo + hi) >> 1; if (a[m] < v) lo = m + 1; else hi = m; }
  return lo;
}

__global__ void k_pool(const float* __restrict__ h, const int* __restrict__ batch,
                       int N, float* __restrict__ out) {
  int g = blockIdx.x;
  int j = threadIdx.x;                     // 128 threads = feature dim
  int lo = lower_bound(batch, N, g);
  int hi = lower_bound(batch, N, g + 1);
  float a0 = 0.f, a1 = 0.f, a2 = 0.f, a3 = 0.f;
  int r = lo;
  for (; r + 3 < hi; r += 4) {
    a0 += h[(size_t)(r + 0) * FEAT + j];
    a1 += h[(size_t)(r + 1) * FEAT + j];
    a2 += h[(size_t)(r + 2) * FEAT + j];
    a3 += h[(size_t)(r + 3) * FEAT + j];
  }
  for (; r < hi; r++) a0 += h[(size_t)r * FEAT + j];
  int cnt = hi - lo;
  float denom = (cnt > 1) ? (float)cnt : 1.0f;
  out[g * FEAT + j] = (a0 + a1 + a2 + a3) / denom;
}

// ---------------- launch ----------------
extern "C" void kernel_launch(void* const* d_in, const int* in_sizes, int n_in,
                              void* d_out, int out_size, void* d_ws, size_t ws_size,
                              hipStream_t stream) {
  const float* x     = (const float*)d_in[0];
  const int*   ei    = (const int*)  d_in[1];
  const int*   batch = (const int*)  d_in[2];
  // d_in[3] = num_graphs scalar (derived from out_size instead)
  const float* W1    = (const float*)d_in[4];
  const float* b1    = (const float*)d_in[5];
  const float* W2    = (const float*)d_in[6];
  const float* b2    = (const float*)d_in[7];

  const int N = in_sizes[0] / FEAT;
  const int E = in_sizes[1] / 2;
  const int G = out_size / FEAT;
  const int* src = ei;
  const int* dst = ei + E;

  char* w = (char*)d_ws;
  float* xw   = (float*)w;  w += (size_t)N * FEAT * 4;
  float* h    = (float*)w;  w += (size_t)N * FEAT * 4;
  int*   deg  = (int*)w;    w += (size_t)N * 4;
  int*   off  = (int*)w;    w += ((size_t)(N + 1) * 4 + 15) & ~(size_t)15;
  int*   aux  = (int*)w;    w += 256 * 4;
  int*   curs = (int*)w;    w += (size_t)N * 4;
  int*   csr  = (int*)w;    w += (size_t)E * 4;
  float* dinv = (float*)w;  w += (size_t)N * 4;

  const int nb = (N + SCAN_B - 1) / SCAN_B;   // 157 <= 256, single-block aux scan ok

  k_zero_int  <<<(N + 255) / 256, 256, 0, stream>>>(deg, N);
  k_degree    <<<(E + 255) / 256, 256, 0, stream>>>(dst, E, deg);
  k_scan_local<<<nb, SCAN_B, 0, stream>>>(deg, N, off, aux);
  k_scan_aux  <<<1, SCAN_B, 0, stream>>>(aux, nb);
  k_finish    <<<nb, SCAN_B, 0, stream>>>(off, aux, deg, dinv, curs, N, E);
  k_fill      <<<(E + 255) / 256, 256, 0, stream>>>(src, dst, E, curs, csr);

  k_gemm_scaled<<<640, 256, 0, stream>>>(x, W1, dinv, xw, N);
  k_prop       <<<(N + 1) / 2, 256, 0, stream>>>(xw, off, csr, dinv, b1, h, N);
  k_gemm_scaled<<<640, 256, 0, stream>>>(h, W2, dinv, xw, N);
  k_prop       <<<(N + 1) / 2, 256, 0, stream>>>(xw, off, csr, dinv, b2, h, N);

  k_pool<<<G, FEAT, 0, stream>>>(h, batch, N, (float*)d_out);
}